// Round 1
// baseline (1452.632 us; speedup 1.0000x reference)
//
#include <hip/hip_runtime.h>

typedef unsigned short ushort_t;
typedef __attribute__((ext_vector_type(8))) short short8;
typedef __attribute__((ext_vector_type(4))) float floatx4;
typedef __attribute__((ext_vector_type(4))) ushort_t us4;

#define HDIM 1024
#define TSTEPS 64

__device__ __forceinline__ ushort_t f2bf(float f) {
  union { float f; unsigned u; } v; v.f = f;
  unsigned r = v.u + 0x7fffu + ((v.u >> 16) & 1u);
  return (ushort_t)(r >> 16);
}

__device__ __forceinline__ void gld16(const void* g, void* l) {
  __builtin_amdgcn_global_load_lds(
      (__attribute__((address_space(1))) void*)g,
      (__attribute__((address_space(3))) void*)l, 16, 0, 0);
}

// C = act(A @ W^T + bias + extra); A:[1024,K] bf16, W:[1024,K] bf16, C:[1024,1024]
// act: 0=relu, 1=tanh, 2=none. Optional bf16 out, fp32 out, actor partial into pacc.
__global__ __launch_bounds__(256) void gemm_bt(
    const ushort_t* __restrict__ A, const ushort_t* __restrict__ W, int K,
    const float* __restrict__ bias, const float* __restrict__ extra,
    ushort_t* __restrict__ outb, float* __restrict__ outf,
    const float* __restrict__ Wa, float* __restrict__ pacc, int step, int act)
{
  __shared__ short As[64 * 64];
  __shared__ short Bs[64 * 64];
  const int t = threadIdx.x;
  const int w = t >> 6, l = t & 63;
  const int m0 = blockIdx.y * 64, n0 = blockIdx.x * 64;
  const int wm = w >> 1, wn = w & 1;
  const int lhi = l >> 4, llo = l & 15;

  floatx4 acc[2][2];
#pragma unroll
  for (int i = 0; i < 2; ++i)
#pragma unroll
    for (int j = 0; j < 2; ++j)
      acc[i][j] = (floatx4){0.f, 0.f, 0.f, 0.f};

  // Staging: tile = 512 chunks of 16B. chunk c holds global (r=c>>3, cb=(c&7)^(r&7))
  // wave w, instr0: c = w*64+l ; instr1: c = 256+w*64+l
  const int r0 = w * 8 + (l >> 3);
  const int cb0 = (l & 7) ^ (r0 & 7);
  const int r1 = 32 + r0;
  const int cb1 = (l & 7) ^ (r1 & 7);
  const ushort_t* Ag0 = A + (size_t)(m0 + r0) * K + cb0 * 8;
  const ushort_t* Ag1 = A + (size_t)(m0 + r1) * K + cb1 * 8;
  const ushort_t* Bg0 = W + (size_t)(n0 + r0) * K + cb0 * 8;
  const ushort_t* Bg1 = W + (size_t)(n0 + r1) * K + cb1 * 8;
  short* As0 = As + w * 512;         // bytes w*1024
  short* As1 = As + 2048 + w * 512;  // bytes 4096 + w*1024
  short* Bs0 = Bs + w * 512;
  short* Bs1 = Bs + 2048 + w * 512;

  for (int kt = 0; kt < K; kt += 64) {
    gld16(Ag0 + kt, As0);
    gld16(Ag1 + kt, As1);
    gld16(Bg0 + kt, Bs0);
    gld16(Bg1 + kt, Bs1);
    __syncthreads();
#pragma unroll
    for (int ks = 0; ks < 2; ++ks) {
      short8 a[2], b[2];
#pragma unroll
      for (int tm = 0; tm < 2; ++tm) {
        int m = wm * 32 + tm * 16 + llo;
        int phys = (ks * 4 + lhi) ^ (m & 7);
        a[tm] = *(const short8*)(As + m * 64 + phys * 8);
      }
#pragma unroll
      for (int tn = 0; tn < 2; ++tn) {
        int n = wn * 32 + tn * 16 + llo;
        int phys = (ks * 4 + lhi) ^ (n & 7);
        b[tn] = *(const short8*)(Bs + n * 64 + phys * 8);
      }
#pragma unroll
      for (int tm = 0; tm < 2; ++tm)
#pragma unroll
        for (int tn = 0; tn < 2; ++tn)
          acc[tm][tn] = __builtin_amdgcn_mfma_f32_16x16x32_bf16(
              a[tm], b[tn], acc[tm][tn], 0, 0, 0);
    }
    __syncthreads();
  }

  // Epilogue: C[m,n] at row=(lane>>4)*4+i, col=lane&15 within each 16x16 tile
  float hv[2][2][4];
#pragma unroll
  for (int tm = 0; tm < 2; ++tm)
#pragma unroll
    for (int tn = 0; tn < 2; ++tn)
#pragma unroll
      for (int i = 0; i < 4; ++i) {
        int gm = m0 + wm * 32 + tm * 16 + lhi * 4 + i;
        int gn = n0 + wn * 32 + tn * 16 + llo;
        float v = acc[tm][tn][i];
        if (bias) v += bias[gn];
        if (extra) v += extra[(size_t)gm * HDIM + gn];
        if (act == 0) v = fmaxf(v, 0.f);
        else if (act == 1) v = tanhf(v);
        if (outb) outb[(size_t)gm * HDIM + gn] = f2bf(v);
        if (outf) outf[(size_t)gm * HDIM + gn] = v;
        hv[tm][tn][i] = v;
      }

  if (pacc) {
#pragma unroll
    for (int tm = 0; tm < 2; ++tm)
#pragma unroll
      for (int i = 0; i < 4; ++i) {
        float s = 0.f;
#pragma unroll
        for (int tn = 0; tn < 2; ++tn)
          s += hv[tm][tn][i] * Wa[n0 + wn * 32 + tn * 16 + llo];
        s += __shfl_xor(s, 1);
        s += __shfl_xor(s, 2);
        s += __shfl_xor(s, 4);
        s += __shfl_xor(s, 8);
        if (llo == 0)
          atomicAdd(&pacc[step * HDIM + m0 + wm * 32 + tm * 16 + lhi * 4 + i], s);
      }
  }
}

__global__ __launch_bounds__(256) void prep(
    const float4* __restrict__ x, const float4* __restrict__ w1,
    const float4* __restrict__ w2, const float4* __restrict__ wih,
    const float4* __restrict__ whh, const float* __restrict__ bih,
    const float* __restrict__ bhh,
    us4* __restrict__ xb, us4* __restrict__ w1b, us4* __restrict__ w2b,
    us4* __restrict__ wihb, us4* __restrict__ whhb, us4* __restrict__ wsumb,
    float* __restrict__ bias)
{
  int i = blockIdx.x * 256 + threadIdx.x;  // 0..1048575
  float4 v = x[i];
  us4 o;
  o.x = f2bf(v.x); o.y = f2bf(v.y); o.z = f2bf(v.z); o.w = f2bf(v.w);
  xb[i] = o;
  float4 u = w1[i];
  o.x = f2bf(u.x); o.y = f2bf(u.y); o.z = f2bf(u.z); o.w = f2bf(u.w);
  w1b[i] = o;
  if (i < 262144) {
    float4 a = w2[i];
    o.x = f2bf(a.x); o.y = f2bf(a.y); o.z = f2bf(a.z); o.w = f2bf(a.w);
    w2b[i] = o;
    float4 p = wih[i];
    o.x = f2bf(p.x); o.y = f2bf(p.y); o.z = f2bf(p.z); o.w = f2bf(p.w);
    wihb[i] = o;
    float4 q = whh[i];
    o.x = f2bf(q.x); o.y = f2bf(q.y); o.z = f2bf(q.z); o.w = f2bf(q.w);
    whhb[i] = o;
    o.x = f2bf(p.x + q.x); o.y = f2bf(p.y + q.y);
    o.z = f2bf(p.z + q.z); o.w = f2bf(p.w + q.w);
    wsumb[i] = o;
  }
  if (i < 256) {
#pragma unroll
    for (int j = 0; j < 4; ++j)
      bias[i * 4 + j] = bih[i * 4 + j] + bhh[i * 4 + j];
  }
}

__global__ __launch_bounds__(256) void finalize_probs(
    const float* __restrict__ pacc, const float* __restrict__ ba,
    float* __restrict__ out)
{
  int i = blockIdx.x * 256 + threadIdx.x;  // 65536
  float v = pacc[i] + ba[0];
  out[i] = 1.f / (1.f + __expf(-v));
}

extern "C" void kernel_launch(void* const* d_in, const int* in_sizes, int n_in,
                              void* d_out, int out_size, void* d_ws, size_t ws_size,
                              hipStream_t stream) {
  const float* x   = (const float*)d_in[0];
  const float* W1  = (const float*)d_in[1];
  const float* b1  = (const float*)d_in[2];
  const float* W2  = (const float*)d_in[3];
  const float* b2  = (const float*)d_in[4];
  const float* Wih = (const float*)d_in[5];
  const float* Whh = (const float*)d_in[6];
  const float* bih = (const float*)d_in[7];
  const float* bhh = (const float*)d_in[8];
  const float* Wa  = (const float*)d_in[9];
  const float* ba  = (const float*)d_in[10];

  char* ws = (char*)d_ws;
  ushort_t* Xb   = (ushort_t*)(ws);                    // 8 MB  [1024,4096]
  ushort_t* W1b  = (ushort_t*)(ws + ((size_t)8  << 20));
  ushort_t* W2b  = (ushort_t*)(ws + ((size_t)16 << 20));
  ushort_t* Wihb = (ushort_t*)(ws + ((size_t)18 << 20));
  ushort_t* Whhb = (ushort_t*)(ws + ((size_t)20 << 20));
  ushort_t* Wsmb = (ushort_t*)(ws + ((size_t)22 << 20));
  ushort_t* X1b  = (ushort_t*)(ws + ((size_t)24 << 20));
  ushort_t* Xlb  = (ushort_t*)(ws + ((size_t)26 << 20));
  ushort_t* Hb0  = (ushort_t*)(ws + ((size_t)28 << 20));
  ushort_t* Hb1  = (ushort_t*)(ws + ((size_t)30 << 20));
  float* xw      = (float*)(ws + ((size_t)32 << 20));  // 4 MB fp32
  float* bias    = (float*)(ws + ((size_t)36 << 20));  // 4 KB
  float* pacc    = (float*)(ws + ((size_t)36 << 20) + 4096);  // 256 KB
  ushort_t* Hb[2] = { Hb0, Hb1 };

  float* probs = (float*)d_out;           // [64,1024]
  float* hxout = (float*)d_out + 65536;   // [1024,1024]

  hipMemsetAsync(pacc, 0, TSTEPS * HDIM * sizeof(float), stream);
  prep<<<4096, 256, 0, stream>>>((const float4*)x, (const float4*)W1,
                                 (const float4*)W2, (const float4*)Wih,
                                 (const float4*)Whh, bih, bhh,
                                 (us4*)Xb, (us4*)W1b, (us4*)W2b,
                                 (us4*)Wihb, (us4*)Whhb, (us4*)Wsmb, bias);
  dim3 g(16, 16);
  // X1 = relu(x @ W1^T + b1)
  gemm_bt<<<g, 256, 0, stream>>>(Xb, W1b, 4096, b1, nullptr, X1b, nullptr,
                                 nullptr, nullptr, 0, 0);
  // x_low = relu(X1 @ W2^T + b2)
  gemm_bt<<<g, 256, 0, stream>>>(X1b, W2b, 1024, b2, nullptr, Xlb, nullptr,
                                 nullptr, nullptr, 0, 0);
  // xw = x_low @ Wih^T  (fp32, no act)
  gemm_bt<<<g, 256, 0, stream>>>(Xlb, Wihb, 1024, nullptr, nullptr, nullptr,
                                 xw, nullptr, nullptr, 0, 2);
  // RNN: h_{t+1} = tanh(inp @ Wih^T + h_t @ Whh^T + bias)
  //   t==0:            x_low @ Wsum^T        (h_0 == x_low == inp)
  //   t%16==0 (t>0):   xw + h_t @ Whh^T
  //   else:            h_t @ Wsum^T
  for (int st = 0; st < TSTEPS; ++st) {
    const ushort_t* Ain = (st == 0) ? Xlb : Hb[st & 1];
    bool flag = (st > 0) && ((st % 16) == 0);
    const ushort_t* Wt = flag ? Whhb : Wsmb;
    const float* ex = flag ? xw : nullptr;
    gemm_bt<<<g, 256, 0, stream>>>(Ain, Wt, 1024, bias, ex, Hb[(st + 1) & 1],
                                   (st == TSTEPS - 1) ? hxout : nullptr,
                                   Wa, pacc, st, 1);
  }
  finalize_probs<<<256, 256, 0, stream>>>(pacc, ba, probs);
}